// Round 14
// baseline (321.459 us; speedup 1.0000x reference)
//
#include <hip/hip_runtime.h>
#include <hip/hip_bf16.h>

#define NEG_SLOPE 0.2f

typedef unsigned int uint;
typedef unsigned short ushort;
typedef __attribute__((ext_vector_type(8))) short short8;
typedef __attribute__((ext_vector_type(4))) float floatx4;

static __device__ __forceinline__ ushort f2bf(float f) {
    uint u = __float_as_uint(f);
    uint r = (u + 0x7fffu + ((u >> 16) & 1u)) >> 16;  // RNE
    return (ushort)r;
}
static __device__ __forceinline__ float bf2f(uint s) {
    return __uint_as_float(s << 16);
}

// ---------------- hist + extended weight prep (disjoint block ranges) ------
// W1e [272][128] bf16: rows 0-255 = W1_src^T; 256+h = ws1 fold (alpha_s);
// 264+h = wc1 fold (alpha_d). W2e [48][256]: 0-31 = W2_src^T; 32 = ws2;
// 33 = wc2; 34-47 zero pad.
__global__ __launch_bounds__(256) void histprep_kernel(
    const int* __restrict__ dst, int* __restrict__ deg, int E, int HB,
    const float* __restrict__ W1_src, const float* __restrict__ a1_src,
    const float* __restrict__ W1_dst, const float* __restrict__ a1_dst,
    const float* __restrict__ W2_src, const float* __restrict__ a2_src,
    const float* __restrict__ W2_dst, const float* __restrict__ a2_dst,
    ushort* __restrict__ W1e, ushort* __restrict__ W2e) {
    if (blockIdx.x < (uint)HB) {
        int i = blockIdx.x * blockDim.x + threadIdx.x;
        int e0 = i * 2;
        if (e0 + 1 < E) {
            int2 d2 = ((const int2*)dst)[i];
            atomicAdd(&deg[d2.x], 1);
            atomicAdd(&deg[d2.y], 1);
        } else if (e0 < E) {
            atomicAdd(&deg[dst[e0]], 1);
        }
        return;
    }
    int i = (blockIdx.x - HB) * blockDim.x + threadIdx.x;
    if (i < 32768) {
        int nc = i & 255, k = i >> 8;
        W1e[nc * 128 + k] = f2bf(W1_src[k * 256 + nc]);
    } else if (i < 34816) {
        int j = i - 32768;
        int h = (j >> 7) & 7, k = j & 127;
        bool is_ws = j < 1024;
        const float* W = is_ws ? W1_src : W1_dst;
        const float* a = is_ws ? a1_src : a1_dst;
        float s = 0.f;
#pragma unroll
        for (int c = 0; c < 32; ++c)
            s += W[k * 256 + h * 32 + c] * a[h * 32 + c];
        W1e[((is_ws ? 256 : 264) + h) * 128 + k] = f2bf(s);
    } else if (i < 34816 + 8192) {
        int j = i - 34816;
        int c = j & 31, k = j >> 5;
        W2e[c * 256 + k] = f2bf(W2_src[k * 32 + c]);
    } else if (i < 34816 + 8192 + 512) {
        int j = i - 34816 - 8192;
        int k = j & 255;
        bool is_ws = j < 256;
        const float* W = is_ws ? W2_src : W2_dst;
        const float* a = is_ws ? a2_src : a2_dst;
        float s = 0.f;
#pragma unroll
        for (int c = 0; c < 32; ++c) s += W[k * 32 + c] * a[c];
        W2e[(is_ws ? 32 : 33) * 256 + k] = f2bf(s);
    } else if (i < 34816 + 8192 + 512 + 3584) {
        int j = i - 34816 - 8192 - 512;
        W2e[34 * 256 + j] = 0;
    }
}

// ---------------- single-pass scan via decoupled lookback ------------------
__global__ __launch_bounds__(256) void scanrs_kernel(
    const int* __restrict__ deg, int* __restrict__ rs,
    int* __restrict__ cursor, int* __restrict__ agg,
    int* __restrict__ flag, int n, int E) {
    __shared__ int sh[256];
    int tid = threadIdx.x;
    int c = blockIdx.x;
    int i = c * 256 + tid;
    int d = (i < n) ? deg[i] : 0;
    sh[tid] = d;
    __syncthreads();
    for (int off = 1; off < 256; off <<= 1) {
        int t = (tid >= off) ? sh[tid - off] : 0;
        __syncthreads();
        sh[tid] += t;
        __syncthreads();
    }
    int incl = sh[tid];
    if (tid == 255) {
        agg[c] = incl;
        __threadfence();
        __hip_atomic_store(&flag[c], 1, __ATOMIC_RELEASE,
                           __HIP_MEMORY_SCOPE_AGENT);
    }
    int vt = 0;
    if (tid < c) {
        while (__hip_atomic_load(&flag[tid], __ATOMIC_ACQUIRE,
                                 __HIP_MEMORY_SCOPE_AGENT) == 0) {}
        vt = agg[tid];
    }
    __syncthreads();
    sh[tid] = vt;
    __syncthreads();
    for (int off = 128; off > 0; off >>= 1) {
        if (tid < off) sh[tid] += sh[tid + off];
        __syncthreads();
    }
    int boff = sh[0];
    if (i < n) {
        int v = incl - d + boff;
        rs[i] = v;
        cursor[i] = v;
    }
    if (c == 0 && tid == 0) rs[n] = E;
}

__global__ __launch_bounds__(256) void fill_kernel(
    const int* __restrict__ src, const int* __restrict__ dst,
    int* __restrict__ cursor, int* __restrict__ csr_src, int E) {
    int i = blockIdx.x * blockDim.x + threadIdx.x;
    int e0 = i * 2;
    if (e0 + 1 < E) {
        int2 d2 = ((const int2*)dst)[i];
        int2 s2 = ((const int2*)src)[i];
        int p0 = atomicAdd(&cursor[d2.x], 1);
        int p1 = atomicAdd(&cursor[d2.y], 1);
        csr_src[p0] = s2.x;
        csr_src[p1] = s2.y;
    } else if (e0 < E) {
        int pos = atomicAdd(&cursor[dst[e0]], 1);
        csr_src[pos] = src[e0];
    }
}

// ---------------- GEMM1 via MFMA, single 32KB LDS (At reused as Out) -------
// grid: M-tiles x 2 N-halves. block = 4 waves, each 64x64 out. nhalf==0
// blocks compute the 16-col alpha tile on waves 0/2. 4 blocks/CU.
__global__ __launch_bounds__(256) void gemm1_mfma(
    const float* __restrict__ x, const ushort* __restrict__ W1e,
    ushort* __restrict__ hs1b, float* __restrict__ as1,
    float* __restrict__ ad1, int n) {
    __shared__ ushort buf[128 * 128];  // 32 KB: At during MFMA, Out after
    int mblk = blockIdx.x >> 1, nhalf = blockIdx.x & 1;
    int m0 = mblk * 128;
    int tid = threadIdx.x;
#pragma unroll
    for (int i = 0; i < 8; ++i) {
        int id = tid + i * 256;
        int m = id >> 4, c = id & 15;
        int gm = m0 + m;
        uint4 pk = {0, 0, 0, 0};
        if (gm < n) {
            const float4* xp = (const float4*)(x + (size_t)gm * 128 + c * 8);
            float4 v0 = xp[0], v1 = xp[1];
            pk.x = (uint)f2bf(v0.x) | ((uint)f2bf(v0.y) << 16);
            pk.y = (uint)f2bf(v0.z) | ((uint)f2bf(v0.w) << 16);
            pk.z = (uint)f2bf(v1.x) | ((uint)f2bf(v1.y) << 16);
            pk.w = (uint)f2bf(v1.z) | ((uint)f2bf(v1.w) << 16);
        }
        *(uint4*)(buf + m * 128 + ((c ^ (m & 15)) * 8)) = pk;
    }
    __syncthreads();
    int wid = tid >> 6, lane = tid & 63;
    int q = lane >> 4, l16 = lane & 15;
    int wm = (wid >> 1) * 64;
    int wn = (wid & 1) * 64;
    int gn0 = nhalf * 128 + wn;
    bool do_e = (nhalf == 0) && ((wid & 1) == 0);
    floatx4 z = {0.f, 0.f, 0.f, 0.f};
    floatx4 acc[4][4];
    floatx4 acc_e[4] = {z, z, z, z};
#pragma unroll
    for (int mt = 0; mt < 4; ++mt)
#pragma unroll
        for (int nt = 0; nt < 4; ++nt) acc[mt][nt] = z;
#pragma unroll
    for (int s = 0; s < 4; ++s) {
        short8 af[4], bf[4];
#pragma unroll
        for (int mt = 0; mt < 4; ++mt) {
            int row = wm + mt * 16 + l16;
            int c = s * 4 + q;
            af[mt] = *(const short8*)(buf + row * 128 + ((c ^ (row & 15)) * 8));
        }
#pragma unroll
        for (int nt = 0; nt < 4; ++nt) {
            int col = gn0 + nt * 16 + l16;
            bf[nt] = *(const short8*)(W1e + col * 128 + s * 32 + q * 8);
        }
#pragma unroll
        for (int mt = 0; mt < 4; ++mt)
#pragma unroll
            for (int nt = 0; nt < 4; ++nt)
                acc[mt][nt] = __builtin_amdgcn_mfma_f32_16x16x32_bf16(
                    af[mt], bf[nt], acc[mt][nt], 0, 0, 0);
        if (do_e) {
            short8 bfe = *(const short8*)(W1e + (256 + l16) * 128 + s * 32 + q * 8);
#pragma unroll
            for (int mt = 0; mt < 4; ++mt)
                acc_e[mt] = __builtin_amdgcn_mfma_f32_16x16x32_bf16(
                    af[mt], bfe, acc_e[mt], 0, 0, 0);
        }
    }
    __syncthreads();  // all MFMA reads of buf complete before overwrite
#pragma unroll
    for (int mt = 0; mt < 4; ++mt)
#pragma unroll
        for (int nt = 0; nt < 4; ++nt) {
            floatx4 a = acc[mt][nt];
            int colL = wn + nt * 16 + l16;
#pragma unroll
            for (int r = 0; r < 4; ++r) {
                int rowL = wm + mt * 16 + q * 4 + r;
                buf[rowL * 128 + (((colL >> 3) ^ (rowL & 15)) * 8) + (colL & 7)]
                    = f2bf(a[r]);
            }
        }
    if (do_e) {
#pragma unroll
        for (int mt = 0; mt < 4; ++mt) {
            floatx4 ae = acc_e[mt];
#pragma unroll
            for (int r = 0; r < 4; ++r) {
                int gm = m0 + wm + mt * 16 + q * 4 + r;
                if (gm < n) {
                    if (l16 < 8) as1[(size_t)gm * 8 + l16] = ae[r];
                    else         ad1[(size_t)gm * 8 + l16 - 8] = ae[r];
                }
            }
        }
    }
    __syncthreads();
#pragma unroll
    for (int i = 0; i < 8; ++i) {
        int id = tid + i * 256;
        int m = id >> 4, c8 = id & 15;
        int gm = m0 + m;
        if (gm < n) {
            uint4 v = *(uint4*)(buf + m * 128 + ((c8 ^ (m & 15)) * 8));
            *(uint4*)(hs1b + (size_t)gm * 256 + nhalf * 128 + c8 * 8) = v;
        }
    }
}

// ---------------- gather layer 1 (round-7 proven version) ------------------
__global__ __launch_bounds__(256) void gather1(
    const int* __restrict__ csr_src, const int* __restrict__ rs,
    const ushort* __restrict__ hs1b, const float* __restrict__ as1,
    const float* __restrict__ ad1, const float* __restrict__ b1,
    ushort* __restrict__ h1b, int n) {
    int gid = blockIdx.x * blockDim.x + threadIdx.x;
    int node = gid >> 6;
    int lane = threadIdx.x & 63;
    if (node >= n) return;
    int j = lane >> 5, l = lane & 31;
    int h = l >> 2;
    float ad_v = ad1[node * 8 + h];
    int start = rs[node], cnt = rs[node + 1] - start;
    float acc0 = 0.f, acc1 = 0.f, acc2 = 0.f, acc3 = 0.f;
    float acc4 = 0.f, acc5 = 0.f, acc6 = 0.f, acc7 = 0.f;
    float dacc = 0.f;
    int i = j;
    for (; i + 2 < cnt; i += 4) {
        int sA = csr_src[start + i];
        int sB = csr_src[start + i + 2];
        float tA = as1[sA * 8 + h] + ad_v;
        float tB = as1[sB * 8 + h] + ad_v;
        uint4 vA = *(const uint4*)(hs1b + (size_t)sA * 256 + l * 8);
        uint4 vB = *(const uint4*)(hs1b + (size_t)sB * 256 + l * 8);
        tA = (tA >= 0.f) ? tA : NEG_SLOPE * tA;
        tB = (tB >= 0.f) ? tB : NEG_SLOPE * tB;
        float wA = __expf(tA);
        float wB = __expf(tB);
        acc0 += bf2f(vA.x & 0xffffu) * wA + bf2f(vB.x & 0xffffu) * wB;
        acc1 += bf2f(vA.x >> 16) * wA + bf2f(vB.x >> 16) * wB;
        acc2 += bf2f(vA.y & 0xffffu) * wA + bf2f(vB.y & 0xffffu) * wB;
        acc3 += bf2f(vA.y >> 16) * wA + bf2f(vB.y >> 16) * wB;
        acc4 += bf2f(vA.z & 0xffffu) * wA + bf2f(vB.z & 0xffffu) * wB;
        acc5 += bf2f(vA.z >> 16) * wA + bf2f(vB.z >> 16) * wB;
        acc6 += bf2f(vA.w & 0xffffu) * wA + bf2f(vB.w & 0xffffu) * wB;
        acc7 += bf2f(vA.w >> 16) * wA + bf2f(vB.w >> 16) * wB;
        dacc += wA + wB;
    }
    for (; i < cnt; i += 2) {
        int s = csr_src[start + i];
        float t = as1[s * 8 + h] + ad_v;
        uint4 v = *(const uint4*)(hs1b + (size_t)s * 256 + l * 8);
        t = (t >= 0.f) ? t : NEG_SLOPE * t;
        float w = __expf(t);
        acc0 += bf2f(v.x & 0xffffu) * w;
        acc1 += bf2f(v.x >> 16) * w;
        acc2 += bf2f(v.y & 0xffffu) * w;
        acc3 += bf2f(v.y >> 16) * w;
        acc4 += bf2f(v.z & 0xffffu) * w;
        acc5 += bf2f(v.z >> 16) * w;
        acc6 += bf2f(v.w & 0xffffu) * w;
        acc7 += bf2f(v.w >> 16) * w;
        dacc += w;
    }
    acc0 += __shfl_xor(acc0, 32, 64);
    acc1 += __shfl_xor(acc1, 32, 64);
    acc2 += __shfl_xor(acc2, 32, 64);
    acc3 += __shfl_xor(acc3, 32, 64);
    acc4 += __shfl_xor(acc4, 32, 64);
    acc5 += __shfl_xor(acc5, 32, 64);
    acc6 += __shfl_xor(acc6, 32, 64);
    acc7 += __shfl_xor(acc7, 32, 64);
    dacc += __shfl_xor(dacc, 32, 64);
    if (j == 0) {
        float inv = 1.f / (dacc + 1e-16f);
        float4 b0 = ((const float4*)b1)[l * 2];
        float4 b4 = ((const float4*)b1)[l * 2 + 1];
        float o0 = fmaxf(fmaf(acc0, inv, b0.x), 0.f);
        float o1 = fmaxf(fmaf(acc1, inv, b0.y), 0.f);
        float o2 = fmaxf(fmaf(acc2, inv, b0.z), 0.f);
        float o3 = fmaxf(fmaf(acc3, inv, b0.w), 0.f);
        float o4 = fmaxf(fmaf(acc4, inv, b4.x), 0.f);
        float o5 = fmaxf(fmaf(acc5, inv, b4.y), 0.f);
        float o6 = fmaxf(fmaf(acc6, inv, b4.z), 0.f);
        float o7 = fmaxf(fmaf(acc7, inv, b4.w), 0.f);
        uint4 pk;
        pk.x = (uint)f2bf(o0) | ((uint)f2bf(o1) << 16);
        pk.y = (uint)f2bf(o2) | ((uint)f2bf(o3) << 16);
        pk.z = (uint)f2bf(o4) | ((uint)f2bf(o5) << 16);
        pk.w = (uint)f2bf(o6) | ((uint)f2bf(o7) << 16);
        *(uint4*)(h1b + (size_t)node * 256 + l * 8) = pk;
    }
}

// ---------------- GEMM2 via MFMA, 64-node tile (36KB LDS, 4 blk/CU) --------
// block = 4 waves; wave wid owns rows wid*16..wid*16+15 (16x32 out + alpha).
__global__ __launch_bounds__(256) void gemm2_mfma(
    const ushort* __restrict__ h1b, const ushort* __restrict__ W2e,
    ushort* __restrict__ hs2b, float* __restrict__ as2,
    float* __restrict__ ad2, int n) {
    __shared__ ushort At[64 * 256];  // 32 KB
    __shared__ ushort Out[64 * 32];  // 4 KB
    int m0 = blockIdx.x * 64;
    int tid = threadIdx.x;
#pragma unroll
    for (int i = 0; i < 8; ++i) {
        int id = tid + i * 256;
        int m = id >> 5, c = id & 31;
        int gm = m0 + m;
        uint4 v = {0, 0, 0, 0};
        if (gm < n) v = *(const uint4*)(h1b + (size_t)gm * 256 + c * 8);
        *(uint4*)(At + m * 256 + ((c ^ (m & 15)) * 8)) = v;
    }
    __syncthreads();
    int wid = tid >> 6, lane = tid & 63;
    int q = lane >> 4, l16 = lane & 15;
    int wm = wid * 16;
    floatx4 z = {0.f, 0.f, 0.f, 0.f};
    floatx4 acc[2] = {z, z};
    floatx4 acc_e = z;
#pragma unroll
    for (int s = 0; s < 8; ++s) {
        int row = wm + l16;
        int c = s * 4 + q;
        short8 af = *(const short8*)(At + row * 256 + ((c ^ (row & 15)) * 8));
        short8 bf0 = *(const short8*)(W2e + l16 * 256 + s * 32 + q * 8);
        short8 bf1 = *(const short8*)(W2e + (16 + l16) * 256 + s * 32 + q * 8);
        short8 bfe = *(const short8*)(W2e + (32 + l16) * 256 + s * 32 + q * 8);
        acc[0] = __builtin_amdgcn_mfma_f32_16x16x32_bf16(af, bf0, acc[0], 0, 0, 0);
        acc[1] = __builtin_amdgcn_mfma_f32_16x16x32_bf16(af, bf1, acc[1], 0, 0, 0);
        acc_e  = __builtin_amdgcn_mfma_f32_16x16x32_bf16(af, bfe, acc_e, 0, 0, 0);
    }
#pragma unroll
    for (int nt = 0; nt < 2; ++nt) {
        floatx4 a = acc[nt];
        int colL = nt * 16 + l16;
#pragma unroll
        for (int r = 0; r < 4; ++r) {
            int rowL = wm + q * 4 + r;
            Out[rowL * 32 + (((colL >> 3) ^ (rowL & 3)) * 8) + (colL & 7)]
                = f2bf(a[r]);
        }
    }
#pragma unroll
    for (int r = 0; r < 4; ++r) {
        int gm = m0 + wm + q * 4 + r;
        if (gm < n) {
            if (l16 == 0) as2[gm] = acc_e[r];
            else if (l16 == 1) ad2[gm] = acc_e[r];
        }
    }
    __syncthreads();
    {
        int id = tid;  // 256 uint4 = 64 rows x 4 chunks
        int c4 = id & 3, m = id >> 2;
        int gm = m0 + m;
        if (gm < n)
            *(uint4*)(hs2b + (size_t)gm * 32 + c4 * 8) =
                *(uint4*)(Out + m * 32 + ((c4 ^ (m & 3)) * 8));
    }
}

// ---------------- gather layer 2 (heads=1): 8 lanes/edge x 8 slots ---------
__global__ __launch_bounds__(256) void gather2(
    const int* __restrict__ csr_src, const int* __restrict__ rs,
    const ushort* __restrict__ hs2b, const float* __restrict__ as2,
    const float* __restrict__ ad2, const float* __restrict__ b2,
    float* __restrict__ out, int n) {
    int gid = blockIdx.x * blockDim.x + threadIdx.x;
    int node = gid >> 6;
    int lane = threadIdx.x & 63;
    if (node >= n) return;
    int g = lane >> 3, l = lane & 7;
    float ad_v = ad2[node];
    int start = rs[node], cnt = rs[node + 1] - start;
    float a0 = 0.f, a1 = 0.f, a2 = 0.f, a3 = 0.f, dacc = 0.f;
    for (int i = g; i < cnt; i += 8) {
        int s = csr_src[start + i];
        float t = as2[s] + ad_v;
        t = (t >= 0.f) ? t : NEG_SLOPE * t;
        float w = __expf(t);
        uint2 v = *(const uint2*)(hs2b + (size_t)s * 32 + l * 4);
        a0 += bf2f(v.x & 0xffffu) * w;
        a1 += bf2f(v.x >> 16) * w;
        a2 += bf2f(v.y & 0xffffu) * w;
        a3 += bf2f(v.y >> 16) * w;
        dacc += w;
    }
#pragma unroll
    for (int m = 8; m <= 32; m <<= 1) {
        a0 += __shfl_xor(a0, m, 64);
        a1 += __shfl_xor(a1, m, 64);
        a2 += __shfl_xor(a2, m, 64);
        a3 += __shfl_xor(a3, m, 64);
        dacc += __shfl_xor(dacc, m, 64);
    }
    if (g == 0) {
        float inv = 1.f / (dacc + 1e-16f);
        float4 bv = ((const float4*)b2)[l];
        float4 o;
        o.x = fmaf(a0, inv, bv.x);
        o.y = fmaf(a1, inv, bv.y);
        o.z = fmaf(a2, inv, bv.z);
        o.w = fmaf(a3, inv, bv.w);
        *(float4*)(out + (size_t)node * 32 + l * 4) = o;
    }
}

extern "C" void kernel_launch(void* const* d_in, const int* in_sizes, int n_in,
                              void* d_out, int out_size, void* d_ws, size_t ws_size,
                              hipStream_t stream) {
    const float* x      = (const float*)d_in[0];
    const int*   eidx   = (const int*)d_in[1];
    const float* W1_src = (const float*)d_in[2];
    const float* W1_dst = (const float*)d_in[3];
    const float* a1_src = (const float*)d_in[4];
    const float* a1_dst = (const float*)d_in[5];
    const float* b1     = (const float*)d_in[6];
    const float* W2_src = (const float*)d_in[7];
    const float* W2_dst = (const float*)d_in[8];
    const float* a2_src = (const float*)d_in[9];
    const float* a2_dst = (const float*)d_in[10];
    const float* b2     = (const float*)d_in[11];

    const int n = in_sizes[0] / 128;    // 50000
    const int E = in_sizes[1] / 2;      // 800000
    const int* srcp = eidx;
    const int* dstp = eidx + E;
    const int nb = (n + 255) / 256;     // 196 chunks

    char* ws = (char*)d_ws;
    size_t o = 0;
    auto alloc = [&](size_t bytes) {
        void* p = ws + o;
        o += (bytes + 255) & ~(size_t)255;
        return p;
    };
    ushort* W1e  = (ushort*)alloc(272 * 128 * 2);
    ushort* W2e  = (ushort*)alloc(48 * 256 * 2);
    ushort* hs1b = (ushort*)alloc((size_t)n * 256 * 2);
    ushort* h1b  = (ushort*)alloc((size_t)n * 256 * 2);
    ushort* hs2b = (ushort*)alloc((size_t)n * 32 * 2);
    float* as1 = (float*)alloc((size_t)n * 8 * 4);
    float* ad1 = (float*)alloc((size_t)n * 8 * 4);
    float* as2 = (float*)alloc((size_t)n * 4);
    float* ad2 = (float*)alloc((size_t)n * 4);
    int* csrmeta = (int*)alloc(((size_t)n + 512) * 4);
    int* deg  = csrmeta;
    int* agg  = csrmeta + n;
    int* flag = csrmeta + n + 256;
    int* rs      = (int*)alloc(((size_t)n + 1) * 4);
    int* cursor  = (int*)alloc((size_t)n * 4);
    int* csr_src = (int*)alloc((size_t)E * 4);

    hipMemsetAsync(csrmeta, 0, ((size_t)n + 512) * sizeof(int), stream);

    const int HB = (E / 2 + 255) / 256;
    const int PB = (34816 + 8192 + 512 + 3584 + 255) / 256;
    histprep_kernel<<<HB + PB, 256, 0, stream>>>(
        dstp, deg, E, HB, W1_src, a1_src, W1_dst, a1_dst,
        W2_src, a2_src, W2_dst, a2_dst, W1e, W2e);
    scanrs_kernel<<<nb, 256, 0, stream>>>(deg, rs, cursor, agg, flag, n, E);
    fill_kernel<<<(E / 2 + 255) / 256, 256, 0, stream>>>(srcp, dstp, cursor,
                                                         csr_src, E);

    // layer 1
    gemm1_mfma<<<((n + 127) / 128) * 2, 256, 0, stream>>>(
        x, W1e, hs1b, as1, ad1, n);
    gather1<<<(n + 3) / 4, 256, 0, stream>>>(
        csr_src, rs, hs1b, as1, ad1, b1, h1b, n);

    // layer 2
    gemm2_mfma<<<(n + 63) / 64, 256, 0, stream>>>(
        h1b, W2e, hs2b, as2, ad2, n);
    gather2<<<(n + 3) / 4, 256, 0, stream>>>(
        csr_src, rs, hs2b, as2, ad2, b2, (float*)d_out, n);
}

// Round 15
// 315.139 us; speedup vs baseline: 1.0201x; 1.0201x over previous
//
#include <hip/hip_runtime.h>
#include <hip/hip_bf16.h>

#define NEG_SLOPE 0.2f

typedef unsigned int uint;
typedef unsigned short ushort;
typedef __attribute__((ext_vector_type(8))) short short8;
typedef __attribute__((ext_vector_type(4))) float floatx4;

static __device__ __forceinline__ ushort f2bf(float f) {
    uint u = __float_as_uint(f);
    uint r = (u + 0x7fffu + ((u >> 16) & 1u)) >> 16;  // RNE
    return (ushort)r;
}
static __device__ __forceinline__ float bf2f(uint s) {
    return __uint_as_float(s << 16);
}

// ---------------- hist + extended weight prep (disjoint block ranges) ------
// W1e [272][128] bf16: rows 0-255 = W1_src^T; 256+h = ws1 fold (alpha_s);
// 264+h = wc1 fold (alpha_d). W2e [48][256]: 0-31 = W2_src^T; 32 = ws2;
// 33 = wc2; 34-47 zero pad.
__global__ __launch_bounds__(256) void histprep_kernel(
    const int* __restrict__ dst, int* __restrict__ deg, int E, int HB,
    const float* __restrict__ W1_src, const float* __restrict__ a1_src,
    const float* __restrict__ W1_dst, const float* __restrict__ a1_dst,
    const float* __restrict__ W2_src, const float* __restrict__ a2_src,
    const float* __restrict__ W2_dst, const float* __restrict__ a2_dst,
    ushort* __restrict__ W1e, ushort* __restrict__ W2e) {
    if (blockIdx.x < (uint)HB) {
        int i = blockIdx.x * blockDim.x + threadIdx.x;
        int e0 = i * 2;
        if (e0 + 1 < E) {
            int2 d2 = ((const int2*)dst)[i];
            atomicAdd(&deg[d2.x], 1);
            atomicAdd(&deg[d2.y], 1);
        } else if (e0 < E) {
            atomicAdd(&deg[dst[e0]], 1);
        }
        return;
    }
    int i = (blockIdx.x - HB) * blockDim.x + threadIdx.x;
    if (i < 32768) {
        int nc = i & 255, k = i >> 8;
        W1e[nc * 128 + k] = f2bf(W1_src[k * 256 + nc]);
    } else if (i < 34816) {
        int j = i - 32768;
        int h = (j >> 7) & 7, k = j & 127;
        bool is_ws = j < 1024;
        const float* W = is_ws ? W1_src : W1_dst;
        const float* a = is_ws ? a1_src : a1_dst;
        float s = 0.f;
#pragma unroll
        for (int c = 0; c < 32; ++c)
            s += W[k * 256 + h * 32 + c] * a[h * 32 + c];
        W1e[((is_ws ? 256 : 264) + h) * 128 + k] = f2bf(s);
    } else if (i < 34816 + 8192) {
        int j = i - 34816;
        int c = j & 31, k = j >> 5;
        W2e[c * 256 + k] = f2bf(W2_src[k * 32 + c]);
    } else if (i < 34816 + 8192 + 512) {
        int j = i - 34816 - 8192;
        int k = j & 255;
        bool is_ws = j < 256;
        const float* W = is_ws ? W2_src : W2_dst;
        const float* a = is_ws ? a2_src : a2_dst;
        float s = 0.f;
#pragma unroll
        for (int c = 0; c < 32; ++c) s += W[k * 32 + c] * a[c];
        W2e[(is_ws ? 32 : 33) * 256 + k] = f2bf(s);
    } else if (i < 34816 + 8192 + 512 + 3584) {
        int j = i - 34816 - 8192 - 512;
        W2e[34 * 256 + j] = 0;
    }
}

// ---------------- single-pass scan via decoupled lookback ------------------
__global__ __launch_bounds__(256) void scanrs_kernel(
    const int* __restrict__ deg, int* __restrict__ rs,
    int* __restrict__ cursor, int* __restrict__ agg,
    int* __restrict__ flag, int n, int E) {
    __shared__ int sh[256];
    int tid = threadIdx.x;
    int c = blockIdx.x;
    int i = c * 256 + tid;
    int d = (i < n) ? deg[i] : 0;
    sh[tid] = d;
    __syncthreads();
    for (int off = 1; off < 256; off <<= 1) {
        int t = (tid >= off) ? sh[tid - off] : 0;
        __syncthreads();
        sh[tid] += t;
        __syncthreads();
    }
    int incl = sh[tid];
    if (tid == 255) {
        agg[c] = incl;
        __threadfence();
        __hip_atomic_store(&flag[c], 1, __ATOMIC_RELEASE,
                           __HIP_MEMORY_SCOPE_AGENT);
    }
    int vt = 0;
    if (tid < c) {
        while (__hip_atomic_load(&flag[tid], __ATOMIC_ACQUIRE,
                                 __HIP_MEMORY_SCOPE_AGENT) == 0) {}
        vt = agg[tid];
    }
    __syncthreads();
    sh[tid] = vt;
    __syncthreads();
    for (int off = 128; off > 0; off >>= 1) {
        if (tid < off) sh[tid] += sh[tid + off];
        __syncthreads();
    }
    int boff = sh[0];
    if (i < n) {
        int v = incl - d + boff;
        rs[i] = v;
        cursor[i] = v;
    }
    if (c == 0 && tid == 0) rs[n] = E;
}

// ---------------- fused fill + GEMM1 (round-13 proven structure) -----------
// blocks [0, GB): GEMM1 M-tile x N-half; single 32KB LDS buffer (At reused
// as Out). blocks [GB, ...): CSR fill, 1 edge/thread, overlapped with GEMM1.
__global__ __launch_bounds__(256) void fillgemm1_kernel(
    const float* __restrict__ x, const ushort* __restrict__ W1e,
    ushort* __restrict__ hs1b, float* __restrict__ as1,
    float* __restrict__ ad1, int n, int GB,
    const int* __restrict__ src, const int* __restrict__ dst,
    int* __restrict__ cursor, int* __restrict__ csr_src, int E) {
    __shared__ ushort buf[128 * 128];  // 32 KB: At during MFMA, Out after
    if (blockIdx.x >= (uint)GB) {
        int e = (blockIdx.x - GB) * blockDim.x + threadIdx.x;
        if (e < E) {
            int d = dst[e];
            int pos = atomicAdd(&cursor[d], 1);
            csr_src[pos] = src[e];
        }
        return;
    }
    int mblk = blockIdx.x >> 1, nhalf = blockIdx.x & 1;
    int m0 = mblk * 128;
    int tid = threadIdx.x;
#pragma unroll
    for (int i = 0; i < 8; ++i) {
        int id = tid + i * 256;
        int m = id >> 4, c = id & 15;
        int gm = m0 + m;
        uint4 pk = {0, 0, 0, 0};
        if (gm < n) {
            const float4* xp = (const float4*)(x + (size_t)gm * 128 + c * 8);
            float4 v0 = xp[0], v1 = xp[1];
            pk.x = (uint)f2bf(v0.x) | ((uint)f2bf(v0.y) << 16);
            pk.y = (uint)f2bf(v0.z) | ((uint)f2bf(v0.w) << 16);
            pk.z = (uint)f2bf(v1.x) | ((uint)f2bf(v1.y) << 16);
            pk.w = (uint)f2bf(v1.z) | ((uint)f2bf(v1.w) << 16);
        }
        *(uint4*)(buf + m * 128 + ((c ^ (m & 15)) * 8)) = pk;
    }
    __syncthreads();
    int wid = tid >> 6, lane = tid & 63;
    int q = lane >> 4, l16 = lane & 15;
    int wm = (wid >> 1) * 64;
    int wn = (wid & 1) * 64;
    int gn0 = nhalf * 128 + wn;
    bool do_e = (nhalf == 0) && ((wid & 1) == 0);
    floatx4 z = {0.f, 0.f, 0.f, 0.f};
    floatx4 acc[4][4];
    floatx4 acc_e[4] = {z, z, z, z};
#pragma unroll
    for (int mt = 0; mt < 4; ++mt)
#pragma unroll
        for (int nt = 0; nt < 4; ++nt) acc[mt][nt] = z;
#pragma unroll
    for (int s = 0; s < 4; ++s) {
        short8 af[4], bf[4];
#pragma unroll
        for (int mt = 0; mt < 4; ++mt) {
            int row = wm + mt * 16 + l16;
            int c = s * 4 + q;
            af[mt] = *(const short8*)(buf + row * 128 + ((c ^ (row & 15)) * 8));
        }
#pragma unroll
        for (int nt = 0; nt < 4; ++nt) {
            int col = gn0 + nt * 16 + l16;
            bf[nt] = *(const short8*)(W1e + col * 128 + s * 32 + q * 8);
        }
#pragma unroll
        for (int mt = 0; mt < 4; ++mt)
#pragma unroll
            for (int nt = 0; nt < 4; ++nt)
                acc[mt][nt] = __builtin_amdgcn_mfma_f32_16x16x32_bf16(
                    af[mt], bf[nt], acc[mt][nt], 0, 0, 0);
        if (do_e) {
            short8 bfe = *(const short8*)(W1e + (256 + l16) * 128 + s * 32 + q * 8);
#pragma unroll
            for (int mt = 0; mt < 4; ++mt)
                acc_e[mt] = __builtin_amdgcn_mfma_f32_16x16x32_bf16(
                    af[mt], bfe, acc_e[mt], 0, 0, 0);
        }
    }
    __syncthreads();  // all MFMA reads of buf complete before overwrite
#pragma unroll
    for (int mt = 0; mt < 4; ++mt)
#pragma unroll
        for (int nt = 0; nt < 4; ++nt) {
            floatx4 a = acc[mt][nt];
            int colL = wn + nt * 16 + l16;
#pragma unroll
            for (int r = 0; r < 4; ++r) {
                int rowL = wm + mt * 16 + q * 4 + r;
                buf[rowL * 128 + (((colL >> 3) ^ (rowL & 15)) * 8) + (colL & 7)]
                    = f2bf(a[r]);
            }
        }
    if (do_e) {
#pragma unroll
        for (int mt = 0; mt < 4; ++mt) {
            floatx4 ae = acc_e[mt];
#pragma unroll
            for (int r = 0; r < 4; ++r) {
                int gm = m0 + wm + mt * 16 + q * 4 + r;
                if (gm < n) {
                    if (l16 < 8) as1[(size_t)gm * 8 + l16] = ae[r];
                    else         ad1[(size_t)gm * 8 + l16 - 8] = ae[r];
                }
            }
        }
    }
    __syncthreads();
#pragma unroll
    for (int i = 0; i < 8; ++i) {
        int id = tid + i * 256;
        int m = id >> 4, c8 = id & 15;
        int gm = m0 + m;
        if (gm < n) {
            uint4 v = *(uint4*)(buf + m * 128 + ((c8 ^ (m & 15)) * 8));
            *(uint4*)(hs1b + (size_t)gm * 256 + nhalf * 128 + c8 * 8) = v;
        }
    }
}

// ---------------- gather layer 1 (round-7 proven version) ------------------
__global__ __launch_bounds__(256) void gather1(
    const int* __restrict__ csr_src, const int* __restrict__ rs,
    const ushort* __restrict__ hs1b, const float* __restrict__ as1,
    const float* __restrict__ ad1, const float* __restrict__ b1,
    ushort* __restrict__ h1b, int n) {
    int gid = blockIdx.x * blockDim.x + threadIdx.x;
    int node = gid >> 6;
    int lane = threadIdx.x & 63;
    if (node >= n) return;
    int j = lane >> 5, l = lane & 31;
    int h = l >> 2;
    float ad_v = ad1[node * 8 + h];
    int start = rs[node], cnt = rs[node + 1] - start;
    float acc0 = 0.f, acc1 = 0.f, acc2 = 0.f, acc3 = 0.f;
    float acc4 = 0.f, acc5 = 0.f, acc6 = 0.f, acc7 = 0.f;
    float dacc = 0.f;
    int i = j;
    for (; i + 2 < cnt; i += 4) {
        int sA = csr_src[start + i];
        int sB = csr_src[start + i + 2];
        float tA = as1[sA * 8 + h] + ad_v;
        float tB = as1[sB * 8 + h] + ad_v;
        uint4 vA = *(const uint4*)(hs1b + (size_t)sA * 256 + l * 8);
        uint4 vB = *(const uint4*)(hs1b + (size_t)sB * 256 + l * 8);
        tA = (tA >= 0.f) ? tA : NEG_SLOPE * tA;
        tB = (tB >= 0.f) ? tB : NEG_SLOPE * tB;
        float wA = __expf(tA);
        float wB = __expf(tB);
        acc0 += bf2f(vA.x & 0xffffu) * wA + bf2f(vB.x & 0xffffu) * wB;
        acc1 += bf2f(vA.x >> 16) * wA + bf2f(vB.x >> 16) * wB;
        acc2 += bf2f(vA.y & 0xffffu) * wA + bf2f(vB.y & 0xffffu) * wB;
        acc3 += bf2f(vA.y >> 16) * wA + bf2f(vB.y >> 16) * wB;
        acc4 += bf2f(vA.z & 0xffffu) * wA + bf2f(vB.z & 0xffffu) * wB;
        acc5 += bf2f(vA.z >> 16) * wA + bf2f(vB.z >> 16) * wB;
        acc6 += bf2f(vA.w & 0xffffu) * wA + bf2f(vB.w & 0xffffu) * wB;
        acc7 += bf2f(vA.w >> 16) * wA + bf2f(vB.w >> 16) * wB;
        dacc += wA + wB;
    }
    for (; i < cnt; i += 2) {
        int s = csr_src[start + i];
        float t = as1[s * 8 + h] + ad_v;
        uint4 v = *(const uint4*)(hs1b + (size_t)s * 256 + l * 8);
        t = (t >= 0.f) ? t : NEG_SLOPE * t;
        float w = __expf(t);
        acc0 += bf2f(v.x & 0xffffu) * w;
        acc1 += bf2f(v.x >> 16) * w;
        acc2 += bf2f(v.y & 0xffffu) * w;
        acc3 += bf2f(v.y >> 16) * w;
        acc4 += bf2f(v.z & 0xffffu) * w;
        acc5 += bf2f(v.z >> 16) * w;
        acc6 += bf2f(v.w & 0xffffu) * w;
        acc7 += bf2f(v.w >> 16) * w;
        dacc += w;
    }
    acc0 += __shfl_xor(acc0, 32, 64);
    acc1 += __shfl_xor(acc1, 32, 64);
    acc2 += __shfl_xor(acc2, 32, 64);
    acc3 += __shfl_xor(acc3, 32, 64);
    acc4 += __shfl_xor(acc4, 32, 64);
    acc5 += __shfl_xor(acc5, 32, 64);
    acc6 += __shfl_xor(acc6, 32, 64);
    acc7 += __shfl_xor(acc7, 32, 64);
    dacc += __shfl_xor(dacc, 32, 64);
    if (j == 0) {
        float inv = 1.f / (dacc + 1e-16f);
        float4 b0 = ((const float4*)b1)[l * 2];
        float4 b4 = ((const float4*)b1)[l * 2 + 1];
        float o0 = fmaxf(fmaf(acc0, inv, b0.x), 0.f);
        float o1 = fmaxf(fmaf(acc1, inv, b0.y), 0.f);
        float o2 = fmaxf(fmaf(acc2, inv, b0.z), 0.f);
        float o3 = fmaxf(fmaf(acc3, inv, b0.w), 0.f);
        float o4 = fmaxf(fmaf(acc4, inv, b4.x), 0.f);
        float o5 = fmaxf(fmaf(acc5, inv, b4.y), 0.f);
        float o6 = fmaxf(fmaf(acc6, inv, b4.z), 0.f);
        float o7 = fmaxf(fmaf(acc7, inv, b4.w), 0.f);
        uint4 pk;
        pk.x = (uint)f2bf(o0) | ((uint)f2bf(o1) << 16);
        pk.y = (uint)f2bf(o2) | ((uint)f2bf(o3) << 16);
        pk.z = (uint)f2bf(o4) | ((uint)f2bf(o5) << 16);
        pk.w = (uint)f2bf(o6) | ((uint)f2bf(o7) << 16);
        *(uint4*)(h1b + (size_t)node * 256 + l * 8) = pk;
    }
}

// ---------------- GEMM2 via MFMA, 64-node tile (36KB LDS, 4 blk/CU) --------
__global__ __launch_bounds__(256) void gemm2_mfma(
    const ushort* __restrict__ h1b, const ushort* __restrict__ W2e,
    ushort* __restrict__ hs2b, float* __restrict__ as2,
    float* __restrict__ ad2, int n) {
    __shared__ ushort At[64 * 256];  // 32 KB
    __shared__ ushort Out[64 * 32];  // 4 KB
    int m0 = blockIdx.x * 64;
    int tid = threadIdx.x;
#pragma unroll
    for (int i = 0; i < 8; ++i) {
        int id = tid + i * 256;
        int m = id >> 5, c = id & 31;
        int gm = m0 + m;
        uint4 v = {0, 0, 0, 0};
        if (gm < n) v = *(const uint4*)(h1b + (size_t)gm * 256 + c * 8);
        *(uint4*)(At + m * 256 + ((c ^ (m & 15)) * 8)) = v;
    }
    __syncthreads();
    int wid = tid >> 6, lane = tid & 63;
    int q = lane >> 4, l16 = lane & 15;
    int wm = wid * 16;
    floatx4 z = {0.f, 0.f, 0.f, 0.f};
    floatx4 acc[2] = {z, z};
    floatx4 acc_e = z;
#pragma unroll
    for (int s = 0; s < 8; ++s) {
        int row = wm + l16;
        int c = s * 4 + q;
        short8 af = *(const short8*)(At + row * 256 + ((c ^ (row & 15)) * 8));
        short8 bf0 = *(const short8*)(W2e + l16 * 256 + s * 32 + q * 8);
        short8 bf1 = *(const short8*)(W2e + (16 + l16) * 256 + s * 32 + q * 8);
        short8 bfe = *(const short8*)(W2e + (32 + l16) * 256 + s * 32 + q * 8);
        acc[0] = __builtin_amdgcn_mfma_f32_16x16x32_bf16(af, bf0, acc[0], 0, 0, 0);
        acc[1] = __builtin_amdgcn_mfma_f32_16x16x32_bf16(af, bf1, acc[1], 0, 0, 0);
        acc_e  = __builtin_amdgcn_mfma_f32_16x16x32_bf16(af, bfe, acc_e, 0, 0, 0);
    }
#pragma unroll
    for (int nt = 0; nt < 2; ++nt) {
        floatx4 a = acc[nt];
        int colL = nt * 16 + l16;
#pragma unroll
        for (int r = 0; r < 4; ++r) {
            int rowL = wm + q * 4 + r;
            Out[rowL * 32 + (((colL >> 3) ^ (rowL & 3)) * 8) + (colL & 7)]
                = f2bf(a[r]);
        }
    }
#pragma unroll
    for (int r = 0; r < 4; ++r) {
        int gm = m0 + wm + q * 4 + r;
        if (gm < n) {
            if (l16 == 0) as2[gm] = acc_e[r];
            else if (l16 == 1) ad2[gm] = acc_e[r];
        }
    }
    __syncthreads();
    {
        int id = tid;  // 256 uint4 = 64 rows x 4 chunks
        int c4 = id & 3, m = id >> 2;
        int gm = m0 + m;
        if (gm < n)
            *(uint4*)(hs2b + (size_t)gm * 32 + c4 * 8) =
                *(uint4*)(Out + m * 32 + ((c4 ^ (m & 3)) * 8));
    }
}

// ---------------- gather layer 2 (heads=1): 8 lanes/edge x 8 slots ---------
__global__ __launch_bounds__(256) void gather2(
    const int* __restrict__ csr_src, const int* __restrict__ rs,
    const ushort* __restrict__ hs2b, const float* __restrict__ as2,
    const float* __restrict__ ad2, const float* __restrict__ b2,
    float* __restrict__ out, int n) {
    int gid = blockIdx.x * blockDim.x + threadIdx.x;
    int node = gid >> 6;
    int lane = threadIdx.x & 63;
    if (node >= n) return;
    int g = lane >> 3, l = lane & 7;
    float ad_v = ad2[node];
    int start = rs[node], cnt = rs[node + 1] - start;
    float a0 = 0.f, a1 = 0.f, a2 = 0.f, a3 = 0.f, dacc = 0.f;
    for (int i = g; i < cnt; i += 8) {
        int s = csr_src[start + i];
        float t = as2[s] + ad_v;
        t = (t >= 0.f) ? t : NEG_SLOPE * t;
        float w = __expf(t);
        uint2 v = *(const uint2*)(hs2b + (size_t)s * 32 + l * 4);
        a0 += bf2f(v.x & 0xffffu) * w;
        a1 += bf2f(v.x >> 16) * w;
        a2 += bf2f(v.y & 0xffffu) * w;
        a3 += bf2f(v.y >> 16) * w;
        dacc += w;
    }
#pragma unroll
    for (int m = 8; m <= 32; m <<= 1) {
        a0 += __shfl_xor(a0, m, 64);
        a1 += __shfl_xor(a1, m, 64);
        a2 += __shfl_xor(a2, m, 64);
        a3 += __shfl_xor(a3, m, 64);
        dacc += __shfl_xor(dacc, m, 64);
    }
    if (g == 0) {
        float inv = 1.f / (dacc + 1e-16f);
        float4 bv = ((const float4*)b2)[l];
        float4 o;
        o.x = fmaf(a0, inv, bv.x);
        o.y = fmaf(a1, inv, bv.y);
        o.z = fmaf(a2, inv, bv.z);
        o.w = fmaf(a3, inv, bv.w);
        *(float4*)(out + (size_t)node * 32 + l * 4) = o;
    }
}

extern "C" void kernel_launch(void* const* d_in, const int* in_sizes, int n_in,
                              void* d_out, int out_size, void* d_ws, size_t ws_size,
                              hipStream_t stream) {
    const float* x      = (const float*)d_in[0];
    const int*   eidx   = (const int*)d_in[1];
    const float* W1_src = (const float*)d_in[2];
    const float* W1_dst = (const float*)d_in[3];
    const float* a1_src = (const float*)d_in[4];
    const float* a1_dst = (const float*)d_in[5];
    const float* b1     = (const float*)d_in[6];
    const float* W2_src = (const float*)d_in[7];
    const float* W2_dst = (const float*)d_in[8];
    const float* a2_src = (const float*)d_in[9];
    const float* a2_dst = (const float*)d_in[10];
    const float* b2     = (const float*)d_in[11];

    const int n = in_sizes[0] / 128;    // 50000
    const int E = in_sizes[1] / 2;      // 800000
    const int* srcp = eidx;
    const int* dstp = eidx + E;
    const int nb = (n + 255) / 256;     // 196 chunks

    char* ws = (char*)d_ws;
    size_t o = 0;
    auto alloc = [&](size_t bytes) {
        void* p = ws + o;
        o += (bytes + 255) & ~(size_t)255;
        return p;
    };
    ushort* W1e  = (ushort*)alloc(272 * 128 * 2);
    ushort* W2e  = (ushort*)alloc(48 * 256 * 2);
    ushort* hs1b = (ushort*)alloc((size_t)n * 256 * 2);
    ushort* h1b  = (ushort*)alloc((size_t)n * 256 * 2);
    ushort* hs2b = (ushort*)alloc((size_t)n * 32 * 2);
    float* as1 = (float*)alloc((size_t)n * 8 * 4);
    float* ad1 = (float*)alloc((size_t)n * 8 * 4);
    float* as2 = (float*)alloc((size_t)n * 4);
    float* ad2 = (float*)alloc((size_t)n * 4);
    int* csrmeta = (int*)alloc(((size_t)n + 512) * 4);
    int* deg  = csrmeta;
    int* agg  = csrmeta + n;
    int* flag = csrmeta + n + 256;
    int* rs      = (int*)alloc(((size_t)n + 1) * 4);
    int* cursor  = (int*)alloc((size_t)n * 4);
    int* csr_src = (int*)alloc((size_t)E * 4);

    hipMemsetAsync(csrmeta, 0, ((size_t)n + 512) * sizeof(int), stream);

    const int HB = (E / 2 + 255) / 256;
    const int PB = (34816 + 8192 + 512 + 3584 + 255) / 256;
    histprep_kernel<<<HB + PB, 256, 0, stream>>>(
        dstp, deg, E, HB, W1_src, a1_src, W1_dst, a1_dst,
        W2_src, a2_src, W2_dst, a2_dst, W1e, W2e);
    scanrs_kernel<<<nb, 256, 0, stream>>>(deg, rs, cursor, agg, flag, n, E);

    // fused: fill (CSR branch) + gemm1 (weights branch) — independent inputs
    const int GB = ((n + 127) / 128) * 2;          // gemm1 blocks (first)
    const int FB = (E + 255) / 256;                // fill blocks (1 edge/thr)
    fillgemm1_kernel<<<GB + FB, 256, 0, stream>>>(
        x, W1e, hs1b, as1, ad1, n, GB, srcp, dstp, cursor, csr_src, E);

    gather1<<<(n + 3) / 4, 256, 0, stream>>>(
        csr_src, rs, hs1b, as1, ad1, b1, h1b, n);

    // layer 2
    gemm2_mfma<<<(n + 63) / 64, 256, 0, stream>>>(
        h1b, W2e, hs2b, as2, ad2, n);
    gather2<<<(n + 3) / 4, 256, 0, stream>>>(
        csr_src, rs, hs2b, as2, ad2, b2, (float*)d_out, n);
}

// Round 16
// 305.035 us; speedup vs baseline: 1.0538x; 1.0331x over previous
//
#include <hip/hip_runtime.h>
#include <hip/hip_bf16.h>

#define NEG_SLOPE 0.2f

typedef unsigned int uint;
typedef unsigned short ushort;
typedef __attribute__((ext_vector_type(8))) short short8;
typedef __attribute__((ext_vector_type(4))) float floatx4;

static __device__ __forceinline__ ushort f2bf(float f) {
    uint u = __float_as_uint(f);
    uint r = (u + 0x7fffu + ((u >> 16) & 1u)) >> 16;  // RNE
    return (ushort)r;
}
static __device__ __forceinline__ float bf2f(uint s) {
    return __uint_as_float(s << 16);
}

// ---------------- hist + extended weight prep (disjoint block ranges) ------
// W1e [272][128] bf16: rows 0-255 = W1_src^T; 256+h = ws1 fold (alpha_s);
// 264+h = wc1 fold (alpha_d). W2e [48][256]: 0-31 = W2_src^T; 32 = ws2;
// 33 = wc2; 34-47 zero pad.
__global__ __launch_bounds__(256) void histprep_kernel(
    const int* __restrict__ dst, int* __restrict__ deg, int E, int HB,
    const float* __restrict__ W1_src, const float* __restrict__ a1_src,
    const float* __restrict__ W1_dst, const float* __restrict__ a1_dst,
    const float* __restrict__ W2_src, const float* __restrict__ a2_src,
    const float* __restrict__ W2_dst, const float* __restrict__ a2_dst,
    ushort* __restrict__ W1e, ushort* __restrict__ W2e) {
    if (blockIdx.x < (uint)HB) {
        int i = blockIdx.x * blockDim.x + threadIdx.x;
        int e0 = i * 2;
        if (e0 + 1 < E) {
            int2 d2 = ((const int2*)dst)[i];
            atomicAdd(&deg[d2.x], 1);
            atomicAdd(&deg[d2.y], 1);
        } else if (e0 < E) {
            atomicAdd(&deg[dst[e0]], 1);
        }
        return;
    }
    int i = (blockIdx.x - HB) * blockDim.x + threadIdx.x;
    if (i < 32768) {
        int nc = i & 255, k = i >> 8;
        W1e[nc * 128 + k] = f2bf(W1_src[k * 256 + nc]);
    } else if (i < 34816) {
        int j = i - 32768;
        int h = (j >> 7) & 7, k = j & 127;
        bool is_ws = j < 1024;
        const float* W = is_ws ? W1_src : W1_dst;
        const float* a = is_ws ? a1_src : a1_dst;
        float s = 0.f;
#pragma unroll
        for (int c = 0; c < 32; ++c)
            s += W[k * 256 + h * 32 + c] * a[h * 32 + c];
        W1e[((is_ws ? 256 : 264) + h) * 128 + k] = f2bf(s);
    } else if (i < 34816 + 8192) {
        int j = i - 34816;
        int c = j & 31, k = j >> 5;
        W2e[c * 256 + k] = f2bf(W2_src[k * 32 + c]);
    } else if (i < 34816 + 8192 + 512) {
        int j = i - 34816 - 8192;
        int k = j & 255;
        bool is_ws = j < 256;
        const float* W = is_ws ? W2_src : W2_dst;
        const float* a = is_ws ? a2_src : a2_dst;
        float s = 0.f;
#pragma unroll
        for (int c = 0; c < 32; ++c) s += W[k * 32 + c] * a[c];
        W2e[(is_ws ? 32 : 33) * 256 + k] = f2bf(s);
    } else if (i < 34816 + 8192 + 512 + 3584) {
        int j = i - 34816 - 8192 - 512;
        W2e[34 * 256 + j] = 0;
    }
}

// ---------------- single-pass scan via decoupled lookback ------------------
__global__ __launch_bounds__(256) void scanrs_kernel(
    const int* __restrict__ deg, int* __restrict__ rs,
    int* __restrict__ cursor, int* __restrict__ agg,
    int* __restrict__ flag, int n, int E) {
    __shared__ int sh[256];
    int tid = threadIdx.x;
    int c = blockIdx.x;
    int i = c * 256 + tid;
    int d = (i < n) ? deg[i] : 0;
    sh[tid] = d;
    __syncthreads();
    for (int off = 1; off < 256; off <<= 1) {
        int t = (tid >= off) ? sh[tid - off] : 0;
        __syncthreads();
        sh[tid] += t;
        __syncthreads();
    }
    int incl = sh[tid];
    if (tid == 255) {
        agg[c] = incl;
        __threadfence();
        __hip_atomic_store(&flag[c], 1, __ATOMIC_RELEASE,
                           __HIP_MEMORY_SCOPE_AGENT);
    }
    int vt = 0;
    if (tid < c) {
        while (__hip_atomic_load(&flag[tid], __ATOMIC_ACQUIRE,
                                 __HIP_MEMORY_SCOPE_AGENT) == 0) {}
        vt = agg[tid];
    }
    __syncthreads();
    sh[tid] = vt;
    __syncthreads();
    for (int off = 128; off > 0; off >>= 1) {
        if (tid < off) sh[tid] += sh[tid + off];
        __syncthreads();
    }
    int boff = sh[0];
    if (i < n) {
        int v = incl - d + boff;
        rs[i] = v;
        cursor[i] = v;
    }
    if (c == 0 && tid == 0) rs[n] = E;
}

// ---------------- fused fill + GEMM1 (round-13 proven structure) -----------
// blocks [0, GB): GEMM1 M-tile x N-half; single 32KB LDS buffer (At reused
// as Out). blocks [GB, ...): CSR fill, 1 edge/thread, overlapped with GEMM1.
__global__ __launch_bounds__(256) void fillgemm1_kernel(
    const float* __restrict__ x, const ushort* __restrict__ W1e,
    ushort* __restrict__ hs1b, float* __restrict__ as1,
    float* __restrict__ ad1, int n, int GB,
    const int* __restrict__ src, const int* __restrict__ dst,
    int* __restrict__ cursor, int* __restrict__ csr_src, int E) {
    __shared__ ushort buf[128 * 128];  // 32 KB: At during MFMA, Out after
    if (blockIdx.x >= (uint)GB) {
        int e = (blockIdx.x - GB) * blockDim.x + threadIdx.x;
        if (e < E) {
            int d = dst[e];
            int pos = atomicAdd(&cursor[d], 1);
            csr_src[pos] = src[e];
        }
        return;
    }
    int mblk = blockIdx.x >> 1, nhalf = blockIdx.x & 1;
    int m0 = mblk * 128;
    int tid = threadIdx.x;
#pragma unroll
    for (int i = 0; i < 8; ++i) {
        int id = tid + i * 256;
        int m = id >> 4, c = id & 15;
        int gm = m0 + m;
        uint4 pk = {0, 0, 0, 0};
        if (gm < n) {
            const float4* xp = (const float4*)(x + (size_t)gm * 128 + c * 8);
            float4 v0 = xp[0], v1 = xp[1];
            pk.x = (uint)f2bf(v0.x) | ((uint)f2bf(v0.y) << 16);
            pk.y = (uint)f2bf(v0.z) | ((uint)f2bf(v0.w) << 16);
            pk.z = (uint)f2bf(v1.x) | ((uint)f2bf(v1.y) << 16);
            pk.w = (uint)f2bf(v1.z) | ((uint)f2bf(v1.w) << 16);
        }
        *(uint4*)(buf + m * 128 + ((c ^ (m & 15)) * 8)) = pk;
    }
    __syncthreads();
    int wid = tid >> 6, lane = tid & 63;
    int q = lane >> 4, l16 = lane & 15;
    int wm = (wid >> 1) * 64;
    int wn = (wid & 1) * 64;
    int gn0 = nhalf * 128 + wn;
    bool do_e = (nhalf == 0) && ((wid & 1) == 0);
    floatx4 z = {0.f, 0.f, 0.f, 0.f};
    floatx4 acc[4][4];
    floatx4 acc_e[4] = {z, z, z, z};
#pragma unroll
    for (int mt = 0; mt < 4; ++mt)
#pragma unroll
        for (int nt = 0; nt < 4; ++nt) acc[mt][nt] = z;
#pragma unroll
    for (int s = 0; s < 4; ++s) {
        short8 af[4], bf[4];
#pragma unroll
        for (int mt = 0; mt < 4; ++mt) {
            int row = wm + mt * 16 + l16;
            int c = s * 4 + q;
            af[mt] = *(const short8*)(buf + row * 128 + ((c ^ (row & 15)) * 8));
        }
#pragma unroll
        for (int nt = 0; nt < 4; ++nt) {
            int col = gn0 + nt * 16 + l16;
            bf[nt] = *(const short8*)(W1e + col * 128 + s * 32 + q * 8);
        }
#pragma unroll
        for (int mt = 0; mt < 4; ++mt)
#pragma unroll
            for (int nt = 0; nt < 4; ++nt)
                acc[mt][nt] = __builtin_amdgcn_mfma_f32_16x16x32_bf16(
                    af[mt], bf[nt], acc[mt][nt], 0, 0, 0);
        if (do_e) {
            short8 bfe = *(const short8*)(W1e + (256 + l16) * 128 + s * 32 + q * 8);
#pragma unroll
            for (int mt = 0; mt < 4; ++mt)
                acc_e[mt] = __builtin_amdgcn_mfma_f32_16x16x32_bf16(
                    af[mt], bfe, acc_e[mt], 0, 0, 0);
        }
    }
    __syncthreads();  // all MFMA reads of buf complete before overwrite
#pragma unroll
    for (int mt = 0; mt < 4; ++mt)
#pragma unroll
        for (int nt = 0; nt < 4; ++nt) {
            floatx4 a = acc[mt][nt];
            int colL = wn + nt * 16 + l16;
#pragma unroll
            for (int r = 0; r < 4; ++r) {
                int rowL = wm + mt * 16 + q * 4 + r;
                buf[rowL * 128 + (((colL >> 3) ^ (rowL & 15)) * 8) + (colL & 7)]
                    = f2bf(a[r]);
            }
        }
    if (do_e) {
#pragma unroll
        for (int mt = 0; mt < 4; ++mt) {
            floatx4 ae = acc_e[mt];
#pragma unroll
            for (int r = 0; r < 4; ++r) {
                int gm = m0 + wm + mt * 16 + q * 4 + r;
                if (gm < n) {
                    if (l16 < 8) as1[(size_t)gm * 8 + l16] = ae[r];
                    else         ad1[(size_t)gm * 8 + l16 - 8] = ae[r];
                }
            }
        }
    }
    __syncthreads();
#pragma unroll
    for (int i = 0; i < 8; ++i) {
        int id = tid + i * 256;
        int m = id >> 4, c8 = id & 15;
        int gm = m0 + m;
        if (gm < n) {
            uint4 v = *(uint4*)(buf + m * 128 + ((c8 ^ (m & 15)) * 8));
            *(uint4*)(hs1b + (size_t)gm * 256 + nhalf * 128 + c8 * 8) = v;
        }
    }
}

// ---------------- gather layer 1 (round-7 proven version) ------------------
__global__ __launch_bounds__(256) void gather1(
    const int* __restrict__ csr_src, const int* __restrict__ rs,
    const ushort* __restrict__ hs1b, const float* __restrict__ as1,
    const float* __restrict__ ad1, const float* __restrict__ b1,
    ushort* __restrict__ h1b, int n) {
    int gid = blockIdx.x * blockDim.x + threadIdx.x;
    int node = gid >> 6;
    int lane = threadIdx.x & 63;
    if (node >= n) return;
    int j = lane >> 5, l = lane & 31;
    int h = l >> 2;
    float ad_v = ad1[node * 8 + h];
    int start = rs[node], cnt = rs[node + 1] - start;
    float acc0 = 0.f, acc1 = 0.f, acc2 = 0.f, acc3 = 0.f;
    float acc4 = 0.f, acc5 = 0.f, acc6 = 0.f, acc7 = 0.f;
    float dacc = 0.f;
    int i = j;
    for (; i + 2 < cnt; i += 4) {
        int sA = csr_src[start + i];
        int sB = csr_src[start + i + 2];
        float tA = as1[sA * 8 + h] + ad_v;
        float tB = as1[sB * 8 + h] + ad_v;
        uint4 vA = *(const uint4*)(hs1b + (size_t)sA * 256 + l * 8);
        uint4 vB = *(const uint4*)(hs1b + (size_t)sB * 256 + l * 8);
        tA = (tA >= 0.f) ? tA : NEG_SLOPE * tA;
        tB = (tB >= 0.f) ? tB : NEG_SLOPE * tB;
        float wA = __expf(tA);
        float wB = __expf(tB);
        acc0 += bf2f(vA.x & 0xffffu) * wA + bf2f(vB.x & 0xffffu) * wB;
        acc1 += bf2f(vA.x >> 16) * wA + bf2f(vB.x >> 16) * wB;
        acc2 += bf2f(vA.y & 0xffffu) * wA + bf2f(vB.y & 0xffffu) * wB;
        acc3 += bf2f(vA.y >> 16) * wA + bf2f(vB.y >> 16) * wB;
        acc4 += bf2f(vA.z & 0xffffu) * wA + bf2f(vB.z & 0xffffu) * wB;
        acc5 += bf2f(vA.z >> 16) * wA + bf2f(vB.z >> 16) * wB;
        acc6 += bf2f(vA.w & 0xffffu) * wA + bf2f(vB.w & 0xffffu) * wB;
        acc7 += bf2f(vA.w >> 16) * wA + bf2f(vB.w >> 16) * wB;
        dacc += wA + wB;
    }
    for (; i < cnt; i += 2) {
        int s = csr_src[start + i];
        float t = as1[s * 8 + h] + ad_v;
        uint4 v = *(const uint4*)(hs1b + (size_t)s * 256 + l * 8);
        t = (t >= 0.f) ? t : NEG_SLOPE * t;
        float w = __expf(t);
        acc0 += bf2f(v.x & 0xffffu) * w;
        acc1 += bf2f(v.x >> 16) * w;
        acc2 += bf2f(v.y & 0xffffu) * w;
        acc3 += bf2f(v.y >> 16) * w;
        acc4 += bf2f(v.z & 0xffffu) * w;
        acc5 += bf2f(v.z >> 16) * w;
        acc6 += bf2f(v.w & 0xffffu) * w;
        acc7 += bf2f(v.w >> 16) * w;
        dacc += w;
    }
    acc0 += __shfl_xor(acc0, 32, 64);
    acc1 += __shfl_xor(acc1, 32, 64);
    acc2 += __shfl_xor(acc2, 32, 64);
    acc3 += __shfl_xor(acc3, 32, 64);
    acc4 += __shfl_xor(acc4, 32, 64);
    acc5 += __shfl_xor(acc5, 32, 64);
    acc6 += __shfl_xor(acc6, 32, 64);
    acc7 += __shfl_xor(acc7, 32, 64);
    dacc += __shfl_xor(dacc, 32, 64);
    if (j == 0) {
        float inv = 1.f / (dacc + 1e-16f);
        float4 b0 = ((const float4*)b1)[l * 2];
        float4 b4 = ((const float4*)b1)[l * 2 + 1];
        float o0 = fmaxf(fmaf(acc0, inv, b0.x), 0.f);
        float o1 = fmaxf(fmaf(acc1, inv, b0.y), 0.f);
        float o2 = fmaxf(fmaf(acc2, inv, b0.z), 0.f);
        float o3 = fmaxf(fmaf(acc3, inv, b0.w), 0.f);
        float o4 = fmaxf(fmaf(acc4, inv, b4.x), 0.f);
        float o5 = fmaxf(fmaf(acc5, inv, b4.y), 0.f);
        float o6 = fmaxf(fmaf(acc6, inv, b4.z), 0.f);
        float o7 = fmaxf(fmaf(acc7, inv, b4.w), 0.f);
        uint4 pk;
        pk.x = (uint)f2bf(o0) | ((uint)f2bf(o1) << 16);
        pk.y = (uint)f2bf(o2) | ((uint)f2bf(o3) << 16);
        pk.z = (uint)f2bf(o4) | ((uint)f2bf(o5) << 16);
        pk.w = (uint)f2bf(o6) | ((uint)f2bf(o7) << 16);
        *(uint4*)(h1b + (size_t)node * 256 + l * 8) = pk;
    }
}

// ---------------- GEMM2 via MFMA, 128-node tile (round-13 version) ---------
__global__ __launch_bounds__(256) void gemm2_mfma(
    const ushort* __restrict__ h1b, const ushort* __restrict__ W2e,
    ushort* __restrict__ hs2b, float* __restrict__ as2,
    float* __restrict__ ad2, int n) {
    __shared__ ushort At[128 * 256];  // 64 KB
    __shared__ ushort Out[128 * 32];  // 8 KB
    int m0 = blockIdx.x * 128;
    int tid = threadIdx.x;
#pragma unroll
    for (int i = 0; i < 16; ++i) {
        int id = tid + i * 256;
        int m = id >> 5, c = id & 31;
        int gm = m0 + m;
        uint4 v = {0, 0, 0, 0};
        if (gm < n) v = *(const uint4*)(h1b + (size_t)gm * 256 + c * 8);
        *(uint4*)(At + m * 256 + ((c ^ (m & 15)) * 8)) = v;
    }
    __syncthreads();
    int wid = tid >> 6, lane = tid & 63;
    int q = lane >> 4, l16 = lane & 15;
    int wm = wid * 32;
    floatx4 z = {0.f, 0.f, 0.f, 0.f};
    floatx4 acc[2][2] = {{z, z}, {z, z}};
    floatx4 acc_e[2] = {z, z};
#pragma unroll
    for (int s = 0; s < 8; ++s) {
        short8 af[2], bf[2];
#pragma unroll
        for (int mt = 0; mt < 2; ++mt) {
            int row = wm + mt * 16 + l16;
            int c = s * 4 + q;
            af[mt] = *(const short8*)(At + row * 256 + ((c ^ (row & 15)) * 8));
        }
#pragma unroll
        for (int nt = 0; nt < 2; ++nt) {
            int col = nt * 16 + l16;
            bf[nt] = *(const short8*)(W2e + col * 256 + s * 32 + q * 8);
        }
        short8 bfe = *(const short8*)(W2e + (32 + l16) * 256 + s * 32 + q * 8);
#pragma unroll
        for (int mt = 0; mt < 2; ++mt) {
#pragma unroll
            for (int nt = 0; nt < 2; ++nt)
                acc[mt][nt] = __builtin_amdgcn_mfma_f32_16x16x32_bf16(
                    af[mt], bf[nt], acc[mt][nt], 0, 0, 0);
            acc_e[mt] = __builtin_amdgcn_mfma_f32_16x16x32_bf16(
                af[mt], bfe, acc_e[mt], 0, 0, 0);
        }
    }
#pragma unroll
    for (int mt = 0; mt < 2; ++mt)
#pragma unroll
        for (int nt = 0; nt < 2; ++nt) {
            floatx4 a = acc[mt][nt];
            int colL = nt * 16 + l16;
#pragma unroll
            for (int r = 0; r < 4; ++r) {
                int rowL = wm + mt * 16 + q * 4 + r;
                Out[rowL * 32 + (((colL >> 3) ^ (rowL & 3)) * 8) + (colL & 7)]
                    = f2bf(a[r]);
            }
        }
#pragma unroll
    for (int mt = 0; mt < 2; ++mt) {
        floatx4 ae = acc_e[mt];
#pragma unroll
        for (int r = 0; r < 4; ++r) {
            int gm = m0 + wm + mt * 16 + q * 4 + r;
            if (gm < n) {
                if (l16 == 0) as2[gm] = ae[r];
                else if (l16 == 1) ad2[gm] = ae[r];
            }
        }
    }
    __syncthreads();
#pragma unroll
    for (int i = 0; i < 2; ++i) {
        int id = tid + i * 256;
        int c4 = id & 3, m = id >> 2;
        int gm = m0 + m;
        if (gm < n)
            *(uint4*)(hs2b + (size_t)gm * 32 + c4 * 8) =
                *(uint4*)(Out + m * 32 + ((c4 ^ (m & 3)) * 8));
    }
}

// ---------------- gather layer 2 (heads=1): 8 lanes/edge x 8 slots ---------
__global__ __launch_bounds__(256) void gather2(
    const int* __restrict__ csr_src, const int* __restrict__ rs,
    const ushort* __restrict__ hs2b, const float* __restrict__ as2,
    const float* __restrict__ ad2, const float* __restrict__ b2,
    float* __restrict__ out, int n) {
    int gid = blockIdx.x * blockDim.x + threadIdx.x;
    int node = gid >> 6;
    int lane = threadIdx.x & 63;
    if (node >= n) return;
    int g = lane >> 3, l = lane & 7;
    float ad_v = ad2[node];
    int start = rs[node], cnt = rs[node + 1] - start;
    float a0 = 0.f, a1 = 0.f, a2 = 0.f, a3 = 0.f, dacc = 0.f;
    for (int i = g; i < cnt; i += 8) {
        int s = csr_src[start + i];
        float t = as2[s] + ad_v;
        t = (t >= 0.f) ? t : NEG_SLOPE * t;
        float w = __expf(t);
        uint2 v = *(const uint2*)(hs2b + (size_t)s * 32 + l * 4);
        a0 += bf2f(v.x & 0xffffu) * w;
        a1 += bf2f(v.x >> 16) * w;
        a2 += bf2f(v.y & 0xffffu) * w;
        a3 += bf2f(v.y >> 16) * w;
        dacc += w;
    }
#pragma unroll
    for (int m = 8; m <= 32; m <<= 1) {
        a0 += __shfl_xor(a0, m, 64);
        a1 += __shfl_xor(a1, m, 64);
        a2 += __shfl_xor(a2, m, 64);
        a3 += __shfl_xor(a3, m, 64);
        dacc += __shfl_xor(dacc, m, 64);
    }
    if (g == 0) {
        float inv = 1.f / (dacc + 1e-16f);
        float4 bv = ((const float4*)b2)[l];
        float4 o;
        o.x = fmaf(a0, inv, bv.x);
        o.y = fmaf(a1, inv, bv.y);
        o.z = fmaf(a2, inv, bv.z);
        o.w = fmaf(a3, inv, bv.w);
        *(float4*)(out + (size_t)node * 32 + l * 4) = o;
    }
}

extern "C" void kernel_launch(void* const* d_in, const int* in_sizes, int n_in,
                              void* d_out, int out_size, void* d_ws, size_t ws_size,
                              hipStream_t stream) {
    const float* x      = (const float*)d_in[0];
    const int*   eidx   = (const int*)d_in[1];
    const float* W1_src = (const float*)d_in[2];
    const float* W1_dst = (const float*)d_in[3];
    const float* a1_src = (const float*)d_in[4];
    const float* a1_dst = (const float*)d_in[5];
    const float* b1     = (const float*)d_in[6];
    const float* W2_src = (const float*)d_in[7];
    const float* W2_dst = (const float*)d_in[8];
    const float* a2_src = (const float*)d_in[9];
    const float* a2_dst = (const float*)d_in[10];
    const float* b2     = (const float*)d_in[11];

    const int n = in_sizes[0] / 128;    // 50000
    const int E = in_sizes[1] / 2;      // 800000
    const int* srcp = eidx;
    const int* dstp = eidx + E;
    const int nb = (n + 255) / 256;     // 196 chunks

    char* ws = (char*)d_ws;
    size_t o = 0;
    auto alloc = [&](size_t bytes) {
        void* p = ws + o;
        o += (bytes + 255) & ~(size_t)255;
        return p;
    };
    ushort* W1e  = (ushort*)alloc(272 * 128 * 2);
    ushort* W2e  = (ushort*)alloc(48 * 256 * 2);
    ushort* hs1b = (ushort*)alloc((size_t)n * 256 * 2);
    ushort* h1b  = (ushort*)alloc((size_t)n * 256 * 2);
    ushort* hs2b = (ushort*)alloc((size_t)n * 32 * 2);
    float* as1 = (float*)alloc((size_t)n * 8 * 4);
    float* ad1 = (float*)alloc((size_t)n * 8 * 4);
    float* as2 = (float*)alloc((size_t)n * 4);
    float* ad2 = (float*)alloc((size_t)n * 4);
    int* csrmeta = (int*)alloc(((size_t)n + 512) * 4);
    int* deg  = csrmeta;
    int* agg  = csrmeta + n;
    int* flag = csrmeta + n + 256;
    int* rs      = (int*)alloc(((size_t)n + 1) * 4);
    int* cursor  = (int*)alloc((size_t)n * 4);
    int* csr_src = (int*)alloc((size_t)E * 4);

    hipMemsetAsync(csrmeta, 0, ((size_t)n + 512) * sizeof(int), stream);

    const int HB = (E / 2 + 255) / 256;
    const int PB = (34816 + 8192 + 512 + 3584 + 255) / 256;
    histprep_kernel<<<HB + PB, 256, 0, stream>>>(
        dstp, deg, E, HB, W1_src, a1_src, W1_dst, a1_dst,
        W2_src, a2_src, W2_dst, a2_dst, W1e, W2e);
    scanrs_kernel<<<nb, 256, 0, stream>>>(deg, rs, cursor, agg, flag, n, E);

    // fused: fill (CSR branch) + gemm1 (weights branch) — independent inputs
    const int GB = ((n + 127) / 128) * 2;          // gemm1 blocks (first)
    const int FB = (E + 255) / 256;                // fill blocks (1 edge/thr)
    fillgemm1_kernel<<<GB + FB, 256, 0, stream>>>(
        x, W1e, hs1b, as1, ad1, n, GB, srcp, dstp, cursor, csr_src, E);

    gather1<<<(n + 3) / 4, 256, 0, stream>>>(
        csr_src, rs, hs1b, as1, ad1, b1, h1b, n);

    // layer 2
    gemm2_mfma<<<(n + 127) / 128, 256, 0, stream>>>(
        h1b, W2e, hs2b, as2, ad2, n);
    gather2<<<(n + 3) / 4, 256, 0, stream>>>(
        csr_src, rs, hs2b, as2, ad2, b2, (float*)d_out, n);
}